// Round 2
// baseline (424.286 us; speedup 1.0000x reference)
//
#include <hip/hip_runtime.h>
#include <math.h>

// LeftPool: out[b,c,h,w] = max(x[b,c,h,w:]) — reverse cummax along W (contiguous, 128).
// One 32-lane segment processes FOUR rows; each lane owns a float4 per row.
// 4 independent load->shuffle-scan->store chains per thread for memory-level
// parallelism; clamped __shfl suffix scan (max is idempotent under dup).

__global__ __launch_bounds__(256) void leftpool_kernel(const float* __restrict__ x,
                                                       float* __restrict__ out) {
    const int seg     = blockIdx.x * 8 + (threadIdx.x >> 5);  // 8 segments per block
    const int l       = threadIdx.x & 31;                     // lane within segment
    const int segBase = threadIdx.x & 32;                     // segment base within wave64

    const size_t r0 = (size_t)seg * 4;                        // 4 rows per segment
    const float4* __restrict__ x0 = (const float4*)(x + (r0 + 0) * 128);
    const float4* __restrict__ x1 = (const float4*)(x + (r0 + 1) * 128);
    const float4* __restrict__ x2 = (const float4*)(x + (r0 + 2) * 128);
    const float4* __restrict__ x3 = (const float4*)(x + (r0 + 3) * 128);

    // 4 independent loads in flight
    float4 a = x0[l];
    float4 b = x1[l];
    float4 c = x2[l];
    float4 d = x3[l];

    // per-lane local max of 4 elements, per row
    float ma = fmaxf(fmaxf(a.x, a.y), fmaxf(a.z, a.w));
    float mb = fmaxf(fmaxf(b.x, b.y), fmaxf(b.z, b.w));
    float mc = fmaxf(fmaxf(c.x, c.y), fmaxf(c.z, c.w));
    float md = fmaxf(fmaxf(d.x, d.y), fmaxf(d.z, d.w));

    // inclusive suffix-max scan across the 32-lane segment, 4 chains interleaved
    #pragma unroll
    for (int off = 1; off < 32; off <<= 1) {
        int src = l + off;
        if (src > 31) src = 31;                 // clamp: max(v, dup) is harmless
        const int sl = segBase + src;
        float oa = __shfl(ma, sl);
        float ob = __shfl(mb, sl);
        float oc = __shfl(mc, sl);
        float od = __shfl(md, sl);
        ma = fmaxf(ma, oa);
        mb = fmaxf(mb, ob);
        mc = fmaxf(mc, oc);
        md = fmaxf(md, od);
    }

    // exclusive suffix (strictly right of this lane's chunk)
    int src1 = l + 1;
    if (src1 > 31) src1 = 31;
    const int sl1 = segBase + src1;
    float ea = __shfl(ma, sl1);
    float eb = __shfl(mb, sl1);
    float ec = __shfl(mc, sl1);
    float ed = __shfl(md, sl1);
    if (l == 31) { ea = -INFINITY; eb = -INFINITY; ec = -INFINITY; ed = -INFINITY; }

    // reverse cummax within each lane's 4 elements, then store
    float4 o;
    o.w = fmaxf(a.w, ea); o.z = fmaxf(a.z, o.w); o.y = fmaxf(a.y, o.z); o.x = fmaxf(a.x, o.y);
    ((float4*)(out + (r0 + 0) * 128))[l] = o;
    o.w = fmaxf(b.w, eb); o.z = fmaxf(b.z, o.w); o.y = fmaxf(b.y, o.z); o.x = fmaxf(b.x, o.y);
    ((float4*)(out + (r0 + 1) * 128))[l] = o;
    o.w = fmaxf(c.w, ec); o.z = fmaxf(c.z, o.w); o.y = fmaxf(c.y, o.z); o.x = fmaxf(c.x, o.y);
    ((float4*)(out + (r0 + 2) * 128))[l] = o;
    o.w = fmaxf(d.w, ed); o.z = fmaxf(d.z, o.w); o.y = fmaxf(d.y, o.z); o.x = fmaxf(d.x, o.y);
    ((float4*)(out + (r0 + 3) * 128))[l] = o;
}

extern "C" void kernel_launch(void* const* d_in, const int* in_sizes, int n_in,
                              void* d_out, int out_size, void* d_ws, size_t ws_size,
                              hipStream_t stream) {
    const float* x = (const float*)d_in[0];
    float* out = (float*)d_out;

    const int W = 128;
    const int rows = in_sizes[0] / W;          // 16*256*128 = 524288
    const int rows_per_block = 32;             // 8 segments * 4 rows each
    dim3 grid(rows / rows_per_block);          // 16384 blocks
    leftpool_kernel<<<grid, 256, 0, stream>>>(x, out);
}